// Round 1
// baseline (322.953 us; speedup 1.0000x reference)
//
#include <hip/hip_runtime.h>
#include <hip/hip_bf16.h>

#define BB 4
#define TT 2048
#define CC 1024
#define HH 16
#define DD 64
#define BT (BB*TT)   // 8192
#define C3 (3*CC)    // 3072
#define LDST 72      // attn LDS row stride in bf16 elems (144 B)
#define QSCALE 0.18033688011112042f   // 0.125 * log2(e)

typedef __attribute__((ext_vector_type(8))) short short8;
typedef __attribute__((ext_vector_type(4))) float f32x4;

__device__ __forceinline__ short f2bs(float f) {
  __hip_bfloat16 h = __float2bfloat16(f);
  return *reinterpret_cast<short*>(&h);
}

__device__ __forceinline__ void gl_lds16(const short* g, short* l) {
  __builtin_amdgcn_global_load_lds(
      (const __attribute__((address_space(1))) void*)(g),
      (__attribute__((address_space(3))) void*)(l), 16, 0, 0);
}

// ---------------------------------------------------------------------------
// P: single prep launch (verified R8, unchanged).
// ---------------------------------------------------------------------------
__global__ __launch_bounds__(256)
void prep(const float* __restrict__ Wa, short* __restrict__ Wat,
          const float* __restrict__ Wp, short* __restrict__ Wpt,
          const float* __restrict__ x, short* __restrict__ Xb)
{
  __shared__ float Lt[64][65];
  const int bx = blockIdx.x;
  if (bx >= 64) {
    size_t chunk = (size_t)(bx - 64) * 16 + blockIdx.y;
    size_t i = (chunk * 256 + threadIdx.x) * 8;
    float4 a = *reinterpret_cast<const float4*>(x + i);
    float4 b = *reinterpret_cast<const float4*>(x + i + 4);
    short8 o;
    o[0] = f2bs(a.x); o[1] = f2bs(a.y); o[2] = f2bs(a.z); o[3] = f2bs(a.w);
    o[4] = f2bs(b.x); o[5] = f2bs(b.y); o[6] = f2bs(b.z); o[7] = f2bs(b.w);
    *reinterpret_cast<short8*>(Xb + i) = o;
    return;
  }
  const bool isA = (bx < 48);
  const float* in  = isA ? Wa  : Wp;
  short*       out = isA ? Wat : Wpt;
  const int N  = isA ? C3 : CC;
  const int n0 = (isA ? bx : bx - 48) * 64;
  const int k0 = blockIdx.y * 64;
  const int cx = threadIdx.x & 15, rr = threadIdx.x >> 4;
#pragma unroll
  for (int p = 0; p < 4; ++p) {
    int kr = p * 16 + rr;
    float4 u = *reinterpret_cast<const float4*>(in + (size_t)(k0 + kr) * N + n0 + cx * 4);
    Lt[kr][cx * 4 + 0] = u.x;
    Lt[kr][cx * 4 + 1] = u.y;
    Lt[kr][cx * 4 + 2] = u.z;
    Lt[kr][cx * 4 + 3] = u.w;
  }
  __syncthreads();
#pragma unroll
  for (int p = 0; p < 4; ++p) {
    int nr = p * 16 + rr;
    short4 o;
    o.x = f2bs(Lt[cx * 4 + 0][nr]);
    o.y = f2bs(Lt[cx * 4 + 1][nr]);
    o.z = f2bs(Lt[cx * 4 + 2][nr]);
    o.w = f2bs(Lt[cx * 4 + 3][nr]);
    *reinterpret_cast<short4*>(out + (size_t)(n0 + nr) * CC + k0 + cx * 4) = o;
  }
}

// ---------------------------------------------------------------------------
// gemm256<QKV>: C[256 x 128] per block, 512 threads = 8 waves (2M x 4N),
// BK=64, double-buffered LDS, ONE __syncthreads per K-tile (T3 minimum
// 2-phase: stage(next) issued before compute(cur); the vmcnt(0)+barrier that
// __syncthreads emits is exactly the dbuf handoff — race-free).
//
// LDS layout per tile: [kc(2)][row][32 cols] bf16 (64 B rows). Conflict-free
// 2-bit chunk swizzle: 16B-chunk index c at row r holds global chunk
// c ^ ((r>>2)&3).  Staging keeps the gl_lds dest LINEAR (HW requirement,
// m104) and pre-swizzles the per-lane GLOBAL source chunk (rule 21); reads
// XOR the same bits.  Bank check: each quarter-wave b128 read (quad fixed,
// 16 rows) now touches every bank exactly 2x = free (m136).
//
// Grid: qkv (24,32)=768 blocks -> 3 perfectly balanced rounds @1 block/CU;
// proj (8,32)=256 blocks -> 1 round.  LDS 96KB/block, acc 64 VGPR.
// ---------------------------------------------------------------------------
template<bool QKV>
__global__ __launch_bounds__(512, 2)
void gemm256(const short* __restrict__ A, const short* __restrict__ Bt,
             const float* __restrict__ bias,
             short* __restrict__ qb, short* __restrict__ kb, short* __restrict__ vb,
             float* __restrict__ out)
{
  __shared__ __align__(16) short As[2][2 * 256 * 32];  // [dbuf][kc][row][32]
  __shared__ __align__(16) short Bs[2][2 * 128 * 32];  // [dbuf][kc][row][32]

  const int t = threadIdx.x;
  const int lane = t & 63;
  const int l16 = lane & 15, quad = lane >> 4;
  const int w = t >> 6;
  const int wr = w >> 2, wc = w & 3;            // 2 x 4 wave grid
  const int row0 = blockIdx.y * 256;
  const int col0 = blockIdx.x * 128;

  // staging: thread t covers row sr = t>>2 (within a 128-row half), chunk
  // c2 = t&3 (16B).  Source chunk pre-swizzled by s(row) = (t>>4)&3 since
  // row = t>>2 => (row>>2)&3 = (t>>4)&3.
  const int sr  = t >> 2;
  const int c2s = (t & 3) ^ ((t >> 4) & 3);
  const short* aSrc = A  + (size_t)(row0 + sr) * CC + c2s * 8;
  const short* bSrc = Bt + (size_t)(col0 + sr) * CC + c2s * 8;

  auto stage = [&](int d, int k0) {
#pragma unroll
    for (int kc = 0; kc < 2; ++kc) {
#pragma unroll
      for (int hf = 0; hf < 2; ++hf)
        gl_lds16(aSrc + (size_t)hf * 128 * CC + k0 + kc * 32,
                 &As[d][kc * 8192 + hf * 4096 + t * 8]);
      gl_lds16(bSrc + k0 + kc * 32, &Bs[d][kc * 4096 + t * 8]);
    }
  };

  f32x4 acc[8][2];
#pragma unroll
  for (int i = 0; i < 8; ++i)
#pragma unroll
    for (int j = 0; j < 2; ++j) acc[i][j] = (f32x4){0.f, 0.f, 0.f, 0.f};

  stage(0, 0);
  __syncthreads();   // vmcnt(0) drain: tile 0 resident

  for (int kt = 0; kt < 16; ++kt) {
    const int cur = kt & 1;
    if (kt < 15) stage(cur ^ 1, (kt + 1) * 64);   // prefetch flies under MFMA
    const short* Ac = As[cur];
    const short* Bc = Bs[cur];
#pragma unroll
    for (int kc = 0; kc < 2; ++kc) {
      short8 bf[2];
#pragma unroll
      for (int j = 0; j < 2; ++j) {
        int rb  = wc * 32 + j * 16 + l16;
        int idx = (kc * 4096 + rb * 32 + quad * 8) ^ (((rb >> 2) & 3) << 3);
        bf[j] = *reinterpret_cast<const short8*>(&Bc[idx]);
      }
#pragma unroll
      for (int i = 0; i < 8; ++i) {
        int ra  = wr * 128 + i * 16 + l16;
        int idx = (kc * 8192 + ra * 32 + quad * 8) ^ (((ra >> 2) & 3) << 3);
        short8 af = *reinterpret_cast<const short8*>(&Ac[idx]);
#pragma unroll
        for (int j = 0; j < 2; ++j)
          acc[i][j] = __builtin_amdgcn_mfma_f32_16x16x32_bf16(af, bf[j], acc[i][j], 0, 0, 0);
      }
    }
    __syncthreads();  // all reads of buf[cur] done + next tile's loads landed
  }

  if constexpr (QKV) {
#pragma unroll
    for (int j = 0; j < 2; ++j) {
      int colb = col0 + wc * 32 + j * 16 + l16;
      int sel  = colb >> 10, cin = colb & 1023;
      int h    = cin >> 6,  dd  = cin & 63;
      float bv = bias[colb];
#pragma unroll
      for (int i = 0; i < 8; ++i)
#pragma unroll
        for (int r = 0; r < 4; ++r) {
          int row = row0 + wr * 128 + i * 16 + quad * 4 + r;
          int bi = row >> 11, tt = row & 2047;
          float val = acc[i][j][r] + bv;
          size_t hb = (size_t)(bi * HH + h);
          if (sel == 0) {
            qb[(hb * TT + tt) * DD + dd] = f2bs(val * QSCALE);
          } else if (sel == 1) {
            kb[(hb * TT + tt) * DD + dd] = f2bs(val);
          } else {
            int tp = (tt & ~63) | (((tt & 15) << 2) | ((tt >> 4) & 3));
            vb[(hb * DD + dd) * TT + tp] = f2bs(val);
          }
        }
    }
  } else {
#pragma unroll
    for (int j = 0; j < 2; ++j) {
      int col = col0 + wc * 32 + j * 16 + l16;
      float bv = bias[col];
#pragma unroll
      for (int i = 0; i < 8; ++i)
#pragma unroll
        for (int r = 0; r < 4; ++r) {
          int row = row0 + wr * 128 + i * 16 + quad * 4 + r;
          out[(size_t)row * CC + col] = acc[i][j][r] + bv;
        }
    }
  }
}

// ---------------------------------------------------------------------------
// K2: MFMA flash attention (verified R6 kernel, unchanged this round).
// ---------------------------------------------------------------------------
__global__ __launch_bounds__(256, 4)
void attn_mfma(const short* __restrict__ Qb, const short* __restrict__ Kb,
               const short* __restrict__ Vb, short* __restrict__ Y)
{
  __shared__ __align__(16) short Ks[64 * LDST];
  __shared__ __align__(16) short Vt[64 * LDST];
  __shared__ __align__(16) short Pw[4 * 16 * LDST];

  const int t    = threadIdx.x;
  const int w    = t >> 6;
  const int lane = t & 63;
  const int l16  = lane & 15;
  const int quad = lane >> 4;

  const int h  = blockIdx.y, bi = blockIdx.z;
  const size_t head = (size_t)(bi * HH + h) * TT * DD;

  short* myP = &Pw[w * 16 * LDST];
  const int sr = t >> 2;
  const int sc = (t & 3) << 4;

  const int qts[2] = { (int)blockIdx.x, 31 - (int)blockIdx.x };

#pragma unroll
  for (int half = 0; half < 2; ++half) {
    const int qt = qts[half];
    const int q0 = qt * 64;

    short8 qf[2];
#pragma unroll
    for (int kc = 0; kc < 2; ++kc)
      qf[kc] = *reinterpret_cast<const short8*>(
          &Qb[head + (size_t)(q0 + w * 16 + l16) * DD + kc * 32 + quad * 8]);

    f32x4 O[4];
#pragma unroll
    for (int dt = 0; dt < 4; ++dt) O[dt] = (f32x4){0.f, 0.f, 0.f, 0.f};
    float lsum[4] = {};

    for (int kt = 0; kt <= qt; ++kt) {
      const int k0 = kt * 64;
      __syncthreads();

      {
        const short* kg = Kb + head + (size_t)(k0 + sr) * DD + sc;
        short8 a = *reinterpret_cast<const short8*>(kg);
        short8 b = *reinterpret_cast<const short8*>(kg + 8);
        *reinterpret_cast<short8*>(&Ks[sr * LDST + sc])     = a;
        *reinterpret_cast<short8*>(&Ks[sr * LDST + sc + 8]) = b;
        const short* vg = Vb + head + (size_t)sr * TT + k0 + sc;
        short8 c = *reinterpret_cast<const short8*>(vg);
        short8 d = *reinterpret_cast<const short8*>(vg + 8);
        *reinterpret_cast<short8*>(&Vt[sr * LDST + sc])     = c;
        *reinterpret_cast<short8*>(&Vt[sr * LDST + sc + 8]) = d;
      }
      __syncthreads();

      short8 kf[4][2];
#pragma unroll
      for (int nt = 0; nt < 4; ++nt)
#pragma unroll
        for (int kc = 0; kc < 2; ++kc)
          kf[nt][kc] = *reinterpret_cast<const short8*>(
              &Ks[(nt * 16 + l16) * LDST + kc * 32 + quad * 8]);

      f32x4 s[4];
#pragma unroll
      for (int nt = 0; nt < 4; ++nt) s[nt] = (f32x4){0.f, 0.f, 0.f, 0.f};
#pragma unroll
      for (int nt = 0; nt < 4; ++nt)
#pragma unroll
        for (int kc = 0; kc < 2; ++kc)
          s[nt] = __builtin_amdgcn_mfma_f32_16x16x32_bf16(qf[kc], kf[nt][kc], s[nt], 0, 0, 0);

      const int rowg_base = q0 + w * 16 + quad * 4;
#pragma unroll
      for (int r = 0; r < 4; ++r) {
        const int rowg = rowg_base + r;
        short pk[4];
#pragma unroll
        for (int nt = 0; nt < 4; ++nt) {
          float e = (k0 + nt * 16 + l16 <= rowg) ? __builtin_amdgcn_exp2f(s[nt][r]) : 0.f;
          lsum[r] += e;
          pk[nt] = f2bs(e);
        }
        short4 p4; p4.x = pk[0]; p4.y = pk[1]; p4.z = pk[2]; p4.w = pk[3];
        *reinterpret_cast<short4*>(&myP[(quad * 4 + r) * LDST + (l16 << 2)]) = p4;
      }

#pragma unroll
      for (int cc = 0; cc < 2; ++cc) {
        short8 pf = *reinterpret_cast<const short8*>(
            &myP[l16 * LDST + cc * 32 + quad * 8]);
#pragma unroll
        for (int dt = 0; dt < 4; ++dt) {
          short8 vf = *reinterpret_cast<const short8*>(
              &Vt[(dt * 16 + l16) * LDST + cc * 32 + quad * 8]);
          O[dt] = __builtin_amdgcn_mfma_f32_16x16x32_bf16(pf, vf, O[dt], 0, 0, 0);
        }
      }
    }

    float linv[4];
#pragma unroll
    for (int r = 0; r < 4; ++r) {
      float s = lsum[r];
      s += __shfl_xor(s, 1);
      s += __shfl_xor(s, 2);
      s += __shfl_xor(s, 4);
      s += __shfl_xor(s, 8);
      linv[r] = 1.f / s;
    }
#pragma unroll
    for (int dt = 0; dt < 4; ++dt)
#pragma unroll
      for (int r = 0; r < 4; ++r) {
        int tg = q0 + w * 16 + quad * 4 + r;
        Y[((size_t)bi * TT + tg) * CC + h * DD + dt * 16 + l16] =
            f2bs(O[dt][r] * linv[r]);
      }
  }
}

// ---------------------------------------------------------------------------
extern "C" void kernel_launch(void* const* d_in, const int* in_sizes, int n_in,
                              void* d_out, int out_size, void* d_ws, size_t ws_size,
                              hipStream_t stream) {
  const float* x  = (const float*)d_in[0];   // [4,2048,1024] fp32
  const float* Wa = (const float*)d_in[1];   // [1024,3072]  fp32
  const float* ba = (const float*)d_in[2];   // [3072]       fp32
  const float* Wp = (const float*)d_in[3];   // [1024,1024]  fp32
  const float* bp = (const float*)d_in[4];   // [1024]       fp32
  float* out = (float*)d_out;                // [4,2048,1024] fp32

  const size_t NELT = (size_t)BB * HH * TT * DD;   // 8388608
  short* qb  = (short*)d_ws;                       // bf16 [B,H,T,D] (pre-scaled)
  short* kb  = qb + NELT;                          // bf16 [B,H,T,D]
  short* vb  = kb + NELT;                          // bf16 [B,H,D,T] (t remapped)
  short* Xb  = vb + NELT;                          // [8192][1024] bf16
  short* Wat = Xb  + (size_t)BT * CC;              // [3072][1024] bf16 (Wa^T)
  short* Wpt = Wat + (size_t)CC * C3;              // [1024][1024] bf16 (Wp^T)
  short* Yb  = Wpt + (size_t)CC * CC;              // [8192][1024] bf16

  prep<<<dim3(64 + 256, 16), 256, 0, stream>>>(Wa, Wat, Wp, Wpt, x, Xb);

  gemm256<true> <<<dim3(C3 / 128, BT / 256), 512, 0, stream>>>(Xb, Wat, ba, qb, kb, vb, nullptr);
  attn_mfma     <<<dim3(16, HH, BB),         256, 0, stream>>>(qb, kb, vb, Yb);
  gemm256<false><<<dim3(CC / 128, BT / 256), 512, 0, stream>>>(Yb, Wpt, bp, nullptr, nullptr, nullptr, out);
}

// Round 2
// 285.729 us; speedup vs baseline: 1.1303x; 1.1303x over previous
//
#include <hip/hip_runtime.h>
#include <hip/hip_bf16.h>

#define BB 4
#define TT 2048
#define CC 1024
#define HH 16
#define DD 64
#define BT (BB*TT)   // 8192
#define C3 (3*CC)    // 3072
#define LDST 72      // attn LDS row stride in bf16 elems (144 B)
#define QSCALE 0.18033688011112042f   // 0.125 * log2(e)

typedef __attribute__((ext_vector_type(8))) short short8;
typedef __attribute__((ext_vector_type(4))) float f32x4;

__device__ __forceinline__ short f2bs(float f) {
  __hip_bfloat16 h = __float2bfloat16(f);
  return *reinterpret_cast<short*>(&h);
}

__device__ __forceinline__ void gl_lds16(const short* g, short* l) {
  __builtin_amdgcn_global_load_lds(
      (const __attribute__((address_space(1))) void*)(g),
      (__attribute__((address_space(3))) void*)(l), 16, 0, 0);
}

// ---------------------------------------------------------------------------
// P: single prep launch (verified R8, unchanged).
// ---------------------------------------------------------------------------
__global__ __launch_bounds__(256)
void prep(const float* __restrict__ Wa, short* __restrict__ Wat,
          const float* __restrict__ Wp, short* __restrict__ Wpt,
          const float* __restrict__ x, short* __restrict__ Xb)
{
  __shared__ float Lt[64][65];
  const int bx = blockIdx.x;
  if (bx >= 64) {
    size_t chunk = (size_t)(bx - 64) * 16 + blockIdx.y;
    size_t i = (chunk * 256 + threadIdx.x) * 8;
    float4 a = *reinterpret_cast<const float4*>(x + i);
    float4 b = *reinterpret_cast<const float4*>(x + i + 4);
    short8 o;
    o[0] = f2bs(a.x); o[1] = f2bs(a.y); o[2] = f2bs(a.z); o[3] = f2bs(a.w);
    o[4] = f2bs(b.x); o[5] = f2bs(b.y); o[6] = f2bs(b.z); o[7] = f2bs(b.w);
    *reinterpret_cast<short8*>(Xb + i) = o;
    return;
  }
  const bool isA = (bx < 48);
  const float* in  = isA ? Wa  : Wp;
  short*       out = isA ? Wat : Wpt;
  const int N  = isA ? C3 : CC;
  const int n0 = (isA ? bx : bx - 48) * 64;
  const int k0 = blockIdx.y * 64;
  const int cx = threadIdx.x & 15, rr = threadIdx.x >> 4;
#pragma unroll
  for (int p = 0; p < 4; ++p) {
    int kr = p * 16 + rr;
    float4 u = *reinterpret_cast<const float4*>(in + (size_t)(k0 + kr) * N + n0 + cx * 4);
    Lt[kr][cx * 4 + 0] = u.x;
    Lt[kr][cx * 4 + 1] = u.y;
    Lt[kr][cx * 4 + 2] = u.z;
    Lt[kr][cx * 4 + 3] = u.w;
  }
  __syncthreads();
#pragma unroll
  for (int p = 0; p < 4; ++p) {
    int nr = p * 16 + rr;
    short4 o;
    o.x = f2bs(Lt[cx * 4 + 0][nr]);
    o.y = f2bs(Lt[cx * 4 + 1][nr]);
    o.z = f2bs(Lt[cx * 4 + 2][nr]);
    o.w = f2bs(Lt[cx * 4 + 3][nr]);
    *reinterpret_cast<short4*>(out + (size_t)(n0 + nr) * CC + k0 + cx * 4) = o;
  }
}

// ---------------------------------------------------------------------------
// gemm256<QKV>: 256x256 tile, BK=64, 512 threads = 8 waves (2M x 4N),
// per-wave 128x64 output (acc 8x4 f32x4 = 128 VGPR).
//
// Pipeline (T3+T4 counted-vmcnt, race-analyzed):
//   per K-tile kt, two phases kc=0,1. Phase = { s_waitcnt vmcnt(4);
//   s_barrier; sched_barrier; 12x ds_read_b128 frags(kc); stage kc-half of
//   tile kt+1 (4 gl_lds) into buf[kt+1 & 1]; setprio(1); 32 MFMA;
//   setprio(0) }.  vmcnt(4) certifies the oldest outstanding half (the one
//   read this phase) has landed while the newest (issued last phase) flies.
//   WAR: stage target buf was last read at tile kt-1, whose reads all waves
//   passed at this phase's barrier -> safe regardless of landing latency.
//   Only the final phase drains vmcnt(0).
//
// LDS: [2 buf][2 kc][256 rows][32] bf16 per matrix = 128 KB total.
//   gl_lds dest is linear per wave (base + lane*16); conflict-spread is via
//   pre-swizzled GLOBAL source chunk (rule 21): LDS slot (r, kc, c) holds
//   global chunk c ^ (r&3); reads XOR the same bits.
//
// Grid: 1-D, bijective XCD-chunked swizzle (nwg divisible by 8: 384 / 128).
// ---------------------------------------------------------------------------
template<bool QKV>
__global__ __launch_bounds__(512, 2)
void gemm256(const short* __restrict__ A, const short* __restrict__ Bt,
             const float* __restrict__ bias,
             short* __restrict__ qb, short* __restrict__ kb, short* __restrict__ vb,
             float* __restrict__ out)
{
  __shared__ __align__(16) short As[2][2 * 256 * 32];  // [buf][kc][row][32]
  __shared__ __align__(16) short Bs[2][2 * 256 * 32];

  const int t = threadIdx.x;
  const int lane = t & 63;
  const int l16 = lane & 15, quad = lane >> 4;
  const int w = t >> 6;
  const int wr = w >> 2, wc = w & 3;            // 2(M) x 4(N) wave grid

  // bijective XCD-chunked block swizzle (nwg % 8 == 0 guaranteed)
  const int per   = gridDim.x >> 3;
  const int chunk = (blockIdx.x & 7) * per + (blockIdx.x >> 3);
  const int NBC   = QKV ? 12 : 4;               // col-tiles
  const int brow  = chunk / NBC, bcol = chunk % NBC;
  const int row0  = brow * 256;
  const int col0  = bcol * 256;

  // stage a kc-half (A 256x32 + B 256x32 = 4 gl_lds/thread) of tile `ktile`
  auto stageHalf = [&](int b, int kc, int ktile) {
#pragma unroll
    for (int q = 0; q < 2; ++q) {
      int gq = (w * 2 + q) * 64 + lane;          // 0..1023 16B-chunk id
      int rq = gq >> 2;                          // row 0..255
      int cs = ((gq & 3) ^ (rq & 3)) << 3;       // swizzled source chunk (elems)
      gl_lds16(A  + (size_t)(row0 + rq) * CC + ktile * 64 + kc * 32 + cs,
               &As[b][kc * 8192 + gq * 8]);
      gl_lds16(Bt + (size_t)(col0 + rq) * CC + ktile * 64 + kc * 32 + cs,
               &Bs[b][kc * 8192 + gq * 8]);
    }
  };

  f32x4 acc[8][4];
#pragma unroll
  for (int i = 0; i < 8; ++i)
#pragma unroll
    for (int j = 0; j < 4; ++j) acc[i][j] = (f32x4){0.f, 0.f, 0.f, 0.f};

  // prologue: tile 0, both halves, into buf 0 (8 gl_lds outstanding)
  stageHalf(0, 0, 0);
  stageHalf(0, 1, 0);

  for (int kt = 0; kt < 16; ++kt) {
    const int cur = kt & 1;
    const short* Ac = As[cur];
    const short* Bc = Bs[cur];
#pragma unroll
    for (int kc = 0; kc < 2; ++kc) {
      if (kt == 15 && kc == 1) {
        asm volatile("s_waitcnt vmcnt(0)" ::: "memory");
      } else {
        asm volatile("s_waitcnt vmcnt(4)" ::: "memory");
      }
      __builtin_amdgcn_s_barrier();
      __builtin_amdgcn_sched_barrier(0);

      short8 af[8], bf[4];
#pragma unroll
      for (int j = 0; j < 4; ++j) {
        int rb = wc * 64 + j * 16 + l16;
        bf[j] = *reinterpret_cast<const short8*>(
            &Bc[kc * 8192 + rb * 32 + (((quad ^ rb) & 3) << 3)]);
      }
#pragma unroll
      for (int i = 0; i < 8; ++i) {
        int ra = wr * 128 + i * 16 + l16;
        af[i] = *reinterpret_cast<const short8*>(
            &Ac[kc * 8192 + ra * 32 + (((quad ^ ra) & 3) << 3)]);
      }

      if (kt < 15) stageHalf(cur ^ 1, kc, kt + 1);

      __builtin_amdgcn_s_setprio(1);
#pragma unroll
      for (int i = 0; i < 8; ++i)
#pragma unroll
        for (int j = 0; j < 4; ++j)
          acc[i][j] = __builtin_amdgcn_mfma_f32_16x16x32_bf16(af[i], bf[j], acc[i][j], 0, 0, 0);
      __builtin_amdgcn_s_setprio(0);
    }
  }

  if constexpr (QKV) {
#pragma unroll
    for (int j = 0; j < 4; ++j) {
      int colb = col0 + wc * 64 + j * 16 + l16;
      int sel  = colb >> 10, cin = colb & 1023;
      int h    = cin >> 6,  dd  = cin & 63;
      float bv = bias[colb];
#pragma unroll
      for (int i = 0; i < 8; ++i)
#pragma unroll
        for (int r = 0; r < 4; ++r) {
          int row = row0 + wr * 128 + i * 16 + quad * 4 + r;
          int bi = row >> 11, tt = row & 2047;
          float val = acc[i][j][r] + bv;
          size_t hb = (size_t)(bi * HH + h);
          if (sel == 0) {
            qb[(hb * TT + tt) * DD + dd] = f2bs(val * QSCALE);
          } else if (sel == 1) {
            kb[(hb * TT + tt) * DD + dd] = f2bs(val);
          } else {
            int tp = (tt & ~63) | (((tt & 15) << 2) | ((tt >> 4) & 3));
            vb[(hb * DD + dd) * TT + tp] = f2bs(val);
          }
        }
    }
  } else {
#pragma unroll
    for (int j = 0; j < 4; ++j) {
      int col = col0 + wc * 64 + j * 16 + l16;
      float bv = bias[col];
#pragma unroll
      for (int i = 0; i < 8; ++i)
#pragma unroll
        for (int r = 0; r < 4; ++r) {
          int row = row0 + wr * 128 + i * 16 + quad * 4 + r;
          out[(size_t)row * CC + col] = acc[i][j][r] + bv;
        }
    }
  }
}

// ---------------------------------------------------------------------------
// K2: MFMA flash attention (verified R6 body). Change this round: bijective
// XCD-chunked remap of the 1024 blocks so each XCD co-resides 8 heads
// (4 MB K/V = L2-sized working set) instead of ~64 heads (32 MB thrash).
// ---------------------------------------------------------------------------
__global__ __launch_bounds__(256, 4)
void attn_mfma(const short* __restrict__ Qb, const short* __restrict__ Kb,
               const short* __restrict__ Vb, short* __restrict__ Y)
{
  __shared__ __align__(16) short Ks[64 * LDST];
  __shared__ __align__(16) short Vt[64 * LDST];
  __shared__ __align__(16) short Pw[4 * 16 * LDST];

  const int t    = threadIdx.x;
  const int w    = t >> 6;
  const int lane = t & 63;
  const int l16  = lane & 15;
  const int quad = lane >> 4;

  // XCD-chunked bijective remap: 1024 blocks -> XCD k owns nb in [128k,128k+128)
  const int linear = blockIdx.x + 16 * (blockIdx.y + 16 * blockIdx.z);
  const int nb  = (linear & 7) * 128 + (linear >> 3);
  const int qt0 = nb & 15;
  const int h   = (nb >> 4) & 15;
  const int bi  = nb >> 8;
  const size_t head = (size_t)(bi * HH + h) * TT * DD;

  short* myP = &Pw[w * 16 * LDST];
  const int sr = t >> 2;
  const int sc = (t & 3) << 4;

  const int qts[2] = { qt0, 31 - qt0 };

#pragma unroll
  for (int half = 0; half < 2; ++half) {
    const int qt = qts[half];
    const int q0 = qt * 64;

    short8 qf[2];
#pragma unroll
    for (int kc = 0; kc < 2; ++kc)
      qf[kc] = *reinterpret_cast<const short8*>(
          &Qb[head + (size_t)(q0 + w * 16 + l16) * DD + kc * 32 + quad * 8]);

    f32x4 O[4];
#pragma unroll
    for (int dt = 0; dt < 4; ++dt) O[dt] = (f32x4){0.f, 0.f, 0.f, 0.f};
    float lsum[4] = {};

    for (int kt = 0; kt <= qt; ++kt) {
      const int k0 = kt * 64;
      __syncthreads();

      {
        const short* kg = Kb + head + (size_t)(k0 + sr) * DD + sc;
        short8 a = *reinterpret_cast<const short8*>(kg);
        short8 b = *reinterpret_cast<const short8*>(kg + 8);
        *reinterpret_cast<short8*>(&Ks[sr * LDST + sc])     = a;
        *reinterpret_cast<short8*>(&Ks[sr * LDST + sc + 8]) = b;
        const short* vg = Vb + head + (size_t)sr * TT + k0 + sc;
        short8 c = *reinterpret_cast<const short8*>(vg);
        short8 d = *reinterpret_cast<const short8*>(vg + 8);
        *reinterpret_cast<short8*>(&Vt[sr * LDST + sc])     = c;
        *reinterpret_cast<short8*>(&Vt[sr * LDST + sc + 8]) = d;
      }
      __syncthreads();

      short8 kf[4][2];
#pragma unroll
      for (int nt = 0; nt < 4; ++nt)
#pragma unroll
        for (int kc = 0; kc < 2; ++kc)
          kf[nt][kc] = *reinterpret_cast<const short8*>(
              &Ks[(nt * 16 + l16) * LDST + kc * 32 + quad * 8]);

      f32x4 s[4];
#pragma unroll
      for (int nt = 0; nt < 4; ++nt) s[nt] = (f32x4){0.f, 0.f, 0.f, 0.f};
#pragma unroll
      for (int nt = 0; nt < 4; ++nt)
#pragma unroll
        for (int kc = 0; kc < 2; ++kc)
          s[nt] = __builtin_amdgcn_mfma_f32_16x16x32_bf16(qf[kc], kf[nt][kc], s[nt], 0, 0, 0);

      const int rowg_base = q0 + w * 16 + quad * 4;
#pragma unroll
      for (int r = 0; r < 4; ++r) {
        const int rowg = rowg_base + r;
        short pk[4];
#pragma unroll
        for (int nt = 0; nt < 4; ++nt) {
          float e = (k0 + nt * 16 + l16 <= rowg) ? __builtin_amdgcn_exp2f(s[nt][r]) : 0.f;
          lsum[r] += e;
          pk[nt] = f2bs(e);
        }
        short4 p4; p4.x = pk[0]; p4.y = pk[1]; p4.z = pk[2]; p4.w = pk[3];
        *reinterpret_cast<short4*>(&myP[(quad * 4 + r) * LDST + (l16 << 2)]) = p4;
      }

#pragma unroll
      for (int cc = 0; cc < 2; ++cc) {
        short8 pf = *reinterpret_cast<const short8*>(
            &myP[l16 * LDST + cc * 32 + quad * 8]);
#pragma unroll
        for (int dt = 0; dt < 4; ++dt) {
          short8 vf = *reinterpret_cast<const short8*>(
              &Vt[(dt * 16 + l16) * LDST + cc * 32 + quad * 8]);
          O[dt] = __builtin_amdgcn_mfma_f32_16x16x32_bf16(pf, vf, O[dt], 0, 0, 0);
        }
      }
    }

    float linv[4];
#pragma unroll
    for (int r = 0; r < 4; ++r) {
      float s = lsum[r];
      s += __shfl_xor(s, 1);
      s += __shfl_xor(s, 2);
      s += __shfl_xor(s, 4);
      s += __shfl_xor(s, 8);
      linv[r] = 1.f / s;
    }
#pragma unroll
    for (int dt = 0; dt < 4; ++dt)
#pragma unroll
      for (int r = 0; r < 4; ++r) {
        int tg = q0 + w * 16 + quad * 4 + r;
        Y[((size_t)bi * TT + tg) * CC + h * DD + dt * 16 + l16] =
            f2bs(O[dt][r] * linv[r]);
      }
  }
}

// ---------------------------------------------------------------------------
extern "C" void kernel_launch(void* const* d_in, const int* in_sizes, int n_in,
                              void* d_out, int out_size, void* d_ws, size_t ws_size,
                              hipStream_t stream) {
  const float* x  = (const float*)d_in[0];   // [4,2048,1024] fp32
  const float* Wa = (const float*)d_in[1];   // [1024,3072]  fp32
  const float* ba = (const float*)d_in[2];   // [3072]       fp32
  const float* Wp = (const float*)d_in[3];   // [1024,1024]  fp32
  const float* bp = (const float*)d_in[4];   // [1024]       fp32
  float* out = (float*)d_out;                // [4,2048,1024] fp32

  const size_t NELT = (size_t)BB * HH * TT * DD;   // 8388608
  short* qb  = (short*)d_ws;                       // bf16 [B,H,T,D] (pre-scaled)
  short* kb  = qb + NELT;                          // bf16 [B,H,T,D]
  short* vb  = kb + NELT;                          // bf16 [B,H,D,T] (t remapped)
  short* Xb  = vb + NELT;                          // [8192][1024] bf16
  short* Wat = Xb  + (size_t)BT * CC;              // [3072][1024] bf16 (Wa^T)
  short* Wpt = Wat + (size_t)CC * C3;              // [1024][1024] bf16 (Wp^T)
  short* Yb  = Wpt + (size_t)CC * CC;              // [8192][1024] bf16

  prep<<<dim3(64 + 256, 16), 256, 0, stream>>>(Wa, Wat, Wp, Wpt, x, Xb);

  gemm256<true> <<<dim3((C3 / 256) * (BT / 256)), 512, 0, stream>>>(Xb, Wat, ba, qb, kb, vb, nullptr);
  attn_mfma     <<<dim3(16, HH, BB),              256, 0, stream>>>(qb, kb, vb, Yb);
  gemm256<false><<<dim3((CC / 256) * (BT / 256)), 512, 0, stream>>>(Yb, Wpt, bp, nullptr, nullptr, nullptr, out);
}

// Round 3
// 283.835 us; speedup vs baseline: 1.1378x; 1.0067x over previous
//
#include <hip/hip_runtime.h>
#include <hip/hip_bf16.h>

#define BB 4
#define TT 2048
#define CC 1024
#define HH 16
#define DD 64
#define BT (BB*TT)   // 8192
#define C3 (3*CC)    // 3072
#define LDST 72      // attn LDS row stride in bf16 elems (144 B)
#define QSCALE 0.18033688011112042f   // 0.125 * log2(e)

typedef __attribute__((ext_vector_type(8))) short short8;
typedef __attribute__((ext_vector_type(4))) float f32x4;

__device__ __forceinline__ short f2bs(float f) {
  __hip_bfloat16 h = __float2bfloat16(f);
  return *reinterpret_cast<short*>(&h);
}

__device__ __forceinline__ void gl_lds16(const short* g, short* l) {
  __builtin_amdgcn_global_load_lds(
      (const __attribute__((address_space(1))) void*)(g),
      (__attribute__((address_space(3))) void*)(l), 16, 0, 0);
}

// ---------------------------------------------------------------------------
// P: single prep launch (verified R8, unchanged).
// ---------------------------------------------------------------------------
__global__ __launch_bounds__(256)
void prep(const float* __restrict__ Wa, short* __restrict__ Wat,
          const float* __restrict__ Wp, short* __restrict__ Wpt,
          const float* __restrict__ x, short* __restrict__ Xb)
{
  __shared__ float Lt[64][65];
  const int bx = blockIdx.x;
  if (bx >= 64) {
    size_t chunk = (size_t)(bx - 64) * 16 + blockIdx.y;
    size_t i = (chunk * 256 + threadIdx.x) * 8;
    float4 a = *reinterpret_cast<const float4*>(x + i);
    float4 b = *reinterpret_cast<const float4*>(x + i + 4);
    short8 o;
    o[0] = f2bs(a.x); o[1] = f2bs(a.y); o[2] = f2bs(a.z); o[3] = f2bs(a.w);
    o[4] = f2bs(b.x); o[5] = f2bs(b.y); o[6] = f2bs(b.z); o[7] = f2bs(b.w);
    *reinterpret_cast<short8*>(Xb + i) = o;
    return;
  }
  const bool isA = (bx < 48);
  const float* in  = isA ? Wa  : Wp;
  short*       out = isA ? Wat : Wpt;
  const int N  = isA ? C3 : CC;
  const int n0 = (isA ? bx : bx - 48) * 64;
  const int k0 = blockIdx.y * 64;
  const int cx = threadIdx.x & 15, rr = threadIdx.x >> 4;
#pragma unroll
  for (int p = 0; p < 4; ++p) {
    int kr = p * 16 + rr;
    float4 u = *reinterpret_cast<const float4*>(in + (size_t)(k0 + kr) * N + n0 + cx * 4);
    Lt[kr][cx * 4 + 0] = u.x;
    Lt[kr][cx * 4 + 1] = u.y;
    Lt[kr][cx * 4 + 2] = u.z;
    Lt[kr][cx * 4 + 3] = u.w;
  }
  __syncthreads();
#pragma unroll
  for (int p = 0; p < 4; ++p) {
    int nr = p * 16 + rr;
    short4 o;
    o.x = f2bs(Lt[cx * 4 + 0][nr]);
    o.y = f2bs(Lt[cx * 4 + 1][nr]);
    o.z = f2bs(Lt[cx * 4 + 2][nr]);
    o.w = f2bs(Lt[cx * 4 + 3][nr]);
    *reinterpret_cast<short4*>(out + (size_t)(n0 + nr) * CC + k0 + cx * 4) = o;
  }
}

// ---------------------------------------------------------------------------
// gemm256<QKV>: 256x256 tile, BK=64, 8 waves (2M x 4N), m201-style 8-phase
// schedule (4 phases per K-tile, 2 K-tiles per dbuf cycle).
//
// LDS per matrix: [2 buf][2 kc][256 rows][32 cols] bf16 = 64 KB (A) + 64 KB
// (B).  Stage quantum = one (matrix, kc) region = 16 KB = 2 gl_lds/thread.
//
// Swizzle (conflict-free, derived): bank of (row r, chunk c, dword i) =
// 16*(r&1) + 4*c + i.  Store global chunk g at slot c = g ^ ((r>>1)&3)
// (involution; applied as pre-swizzled GLOBAL source so the gl_lds dest
// stays linear, rule 21).  A quarter-wave read (quad fixed, 16 consecutive
// rows) then covers all 32 banks exactly 2x = wave64 minimum = free.
//
// Phase(u, ph): kc=ph>>1, q=ph&1.
//   reads: A-frags quarter q (4x b128) + B-frags (4x b128, q==0 only, kept)
//   stage: ph0->A.kc1(u+1), ph1->B.kc1(u+1), ph2->A.kc0(u+2), ph3->B.kc0(u+2)
//   barrier; lgkmcnt(0); sched_barrier; setprio(1); 16 MFMA; setprio(0);
//   [vmcnt(8) at ph1/ph3 only -- certifies the quanta consumed 2 phases
//    later; placed BEFORE barrier2 so the barrier makes it block-wide];
//   barrier.
// Hazards: region read in phase p completes at p's lgkmcnt(0) < barrier2;
// stage into it is issued in a later phase after barrier2 -> WAR safe.
// Epilogue peel: u=14.ph3 -> vmcnt(4), u=15.ph1 -> vmcnt(0) (exact counts).
// ---------------------------------------------------------------------------
template<bool QKV>
__global__ __launch_bounds__(512, 2)
void gemm256(const short* __restrict__ A, const short* __restrict__ Bt,
             const float* __restrict__ bias,
             short* __restrict__ qb, short* __restrict__ kb, short* __restrict__ vb,
             float* __restrict__ out)
{
  __shared__ __align__(16) short As[2][2 * 256 * 32];  // [buf][kc][row][32]
  __shared__ __align__(16) short Bs[2][2 * 256 * 32];

  const int t = threadIdx.x;
  const int lane = t & 63;
  const int l16 = lane & 15, quad = lane >> 4;
  const int w = t >> 6;
  const int wr = w >> 2, wc = w & 3;            // 2(M) x 4(N) wave grid

  // bijective XCD-chunked block swizzle (nwg % 8 == 0: 384 / 128)
  const int per   = gridDim.x >> 3;
  const int chunk = (blockIdx.x & 7) * per + (blockIdx.x >> 3);
  const int NBC   = QKV ? 12 : 4;               // col-tiles
  const int brow  = chunk / NBC, bcol = chunk % NBC;
  const int row0  = brow * 256;
  const int col0  = bcol * 256;

  // stage one (matrix, kc) quantum of K-tile `tileS` into buffer `bufS`.
  auto stageQ = [&](int bufS, int kcS, int tileS, bool isA) {
#pragma unroll
    for (int l = 0; l < 2; ++l) {
      int gq = l * 512 + t;                 // 16B-chunk id 0..1023
      int rq = gq >> 2;                     // row 0..255
      int g  = (gq & 3) ^ ((rq >> 1) & 3);  // global chunk for this slot
      if (isA) {
        gl_lds16(A + (size_t)(row0 + rq) * CC + tileS * 64 + kcS * 32 + g * 8,
                 &As[bufS][kcS * 8192 + gq * 8]);
      } else {
        gl_lds16(Bt + (size_t)(col0 + rq) * CC + tileS * 64 + kcS * 32 + g * 8,
                 &Bs[bufS][kcS * 8192 + gq * 8]);
      }
    }
  };

  f32x4 acc[8][4];
#pragma unroll
  for (int i = 0; i < 8; ++i)
#pragma unroll
    for (int j = 0; j < 4; ++j) acc[i][j] = (f32x4){0.f, 0.f, 0.f, 0.f};

  // prologue: 6 quanta in steady-state issue order (12 loads/thread)
  stageQ(0, 0, 0, true);  stageQ(0, 0, 0, false);   // A.kc0(0), B.kc0(0)
  stageQ(0, 1, 0, true);  stageQ(0, 1, 0, false);   // A.kc1(0), B.kc1(0)
  stageQ(1, 0, 1, true);  stageQ(1, 0, 1, false);   // A.kc0(1), B.kc0(1)
  asm volatile("s_waitcnt vmcnt(8)" ::: "memory");  // oldest 4 loads (kc0 of t0)
  __builtin_amdgcn_s_barrier();

#pragma unroll
  for (int u = 0; u < 16; ++u) {
    const int cb = u & 1;
    const short* Ac = As[cb];
    const short* Bc = Bs[cb];
    short8 bf[4];
#pragma unroll
    for (int ph = 0; ph < 4; ++ph) {
      const int kc = ph >> 1, q = ph & 1;

      if (q == 0) {
#pragma unroll
        for (int j = 0; j < 4; ++j) {
          int rb = wc * 64 + j * 16 + l16;
          bf[j] = *reinterpret_cast<const short8*>(
              &Bc[kc * 8192 + rb * 32 + (((quad ^ (rb >> 1)) & 3) << 3)]);
        }
      }
      short8 af[4];
#pragma unroll
      for (int iq = 0; iq < 4; ++iq) {
        int ra = wr * 128 + (q * 4 + iq) * 16 + l16;
        af[iq] = *reinterpret_cast<const short8*>(
            &Ac[kc * 8192 + ra * 32 + (((quad ^ (ra >> 1)) & 3) << 3)]);
      }

      // stage one quantum (order: A1,B1 of u+1; A0,B0 of u+2)
      if      (ph == 0) { if (u < 15) stageQ((u + 1) & 1, 1, u + 1, true ); }
      else if (ph == 1) { if (u < 15) stageQ((u + 1) & 1, 1, u + 1, false); }
      else if (ph == 2) { if (u < 14) stageQ(u & 1,       0, u + 2, true ); }
      else              { if (u < 14) stageQ(u & 1,       0, u + 2, false); }

      __builtin_amdgcn_s_barrier();
      asm volatile("s_waitcnt lgkmcnt(0)" ::: "memory");
      __builtin_amdgcn_sched_barrier(0);

      __builtin_amdgcn_s_setprio(1);
#pragma unroll
      for (int iq = 0; iq < 4; ++iq)
#pragma unroll
        for (int j = 0; j < 4; ++j)
          acc[q * 4 + iq][j] =
              __builtin_amdgcn_mfma_f32_16x16x32_bf16(af[iq], bf[j], acc[q * 4 + iq][j], 0, 0, 0);
      __builtin_amdgcn_s_setprio(0);

      // counted vmcnt before barrier2, kc boundaries only (never 0 mid-loop)
      if (ph == 1) {
        if (u == 15)      { asm volatile("s_waitcnt vmcnt(0)" ::: "memory"); }
        else              { asm volatile("s_waitcnt vmcnt(8)" ::: "memory"); }
      } else if (ph == 3) {
        if (u < 14)       { asm volatile("s_waitcnt vmcnt(8)" ::: "memory"); }
        else if (u == 14) { asm volatile("s_waitcnt vmcnt(4)" ::: "memory"); }
      }
      __builtin_amdgcn_s_barrier();
    }
  }

  if constexpr (QKV) {
#pragma unroll
    for (int j = 0; j < 4; ++j) {
      int colb = col0 + wc * 64 + j * 16 + l16;
      int sel  = colb >> 10, cin = colb & 1023;
      int h    = cin >> 6,  dd  = cin & 63;
      float bv = bias[colb];
#pragma unroll
      for (int i = 0; i < 8; ++i)
#pragma unroll
        for (int r = 0; r < 4; ++r) {
          int row = row0 + wr * 128 + i * 16 + quad * 4 + r;
          int bi = row >> 11, tt = row & 2047;
          float val = acc[i][j][r] + bv;
          size_t hb = (size_t)(bi * HH + h);
          if (sel == 0) {
            qb[(hb * TT + tt) * DD + dd] = f2bs(val * QSCALE);
          } else if (sel == 1) {
            kb[(hb * TT + tt) * DD + dd] = f2bs(val);
          } else {
            int tp = (tt & ~63) | (((tt & 15) << 2) | ((tt >> 4) & 3));
            vb[(hb * DD + dd) * TT + tp] = f2bs(val);
          }
        }
    }
  } else {
#pragma unroll
    for (int j = 0; j < 4; ++j) {
      int col = col0 + wc * 64 + j * 16 + l16;
      float bv = bias[col];
#pragma unroll
      for (int i = 0; i < 8; ++i)
#pragma unroll
        for (int r = 0; r < 4; ++r) {
          int row = row0 + wr * 128 + i * 16 + quad * 4 + r;
          out[(size_t)row * CC + col] = acc[i][j][r] + bv;
        }
    }
  }
}

// ---------------------------------------------------------------------------
// K2: MFMA flash attention (verified R6 body + XCD remap). This round:
// T5 setprio around both MFMA clusters (m191: +4-7% on attn).
// ---------------------------------------------------------------------------
__global__ __launch_bounds__(256, 4)
void attn_mfma(const short* __restrict__ Qb, const short* __restrict__ Kb,
               const short* __restrict__ Vb, short* __restrict__ Y)
{
  __shared__ __align__(16) short Ks[64 * LDST];
  __shared__ __align__(16) short Vt[64 * LDST];
  __shared__ __align__(16) short Pw[4 * 16 * LDST];

  const int t    = threadIdx.x;
  const int w    = t >> 6;
  const int lane = t & 63;
  const int l16  = lane & 15;
  const int quad = lane >> 4;

  // XCD-chunked bijective remap: 1024 blocks -> XCD k owns nb in [128k,128k+128)
  const int linear = blockIdx.x + 16 * (blockIdx.y + 16 * blockIdx.z);
  const int nb  = (linear & 7) * 128 + (linear >> 3);
  const int qt0 = nb & 15;
  const int h   = (nb >> 4) & 15;
  const int bi  = nb >> 8;
  const size_t head = (size_t)(bi * HH + h) * TT * DD;

  short* myP = &Pw[w * 16 * LDST];
  const int sr = t >> 2;
  const int sc = (t & 3) << 4;

  const int qts[2] = { qt0, 31 - qt0 };

#pragma unroll
  for (int half = 0; half < 2; ++half) {
    const int qt = qts[half];
    const int q0 = qt * 64;

    short8 qf[2];
#pragma unroll
    for (int kc = 0; kc < 2; ++kc)
      qf[kc] = *reinterpret_cast<const short8*>(
          &Qb[head + (size_t)(q0 + w * 16 + l16) * DD + kc * 32 + quad * 8]);

    f32x4 O[4];
#pragma unroll
    for (int dt = 0; dt < 4; ++dt) O[dt] = (f32x4){0.f, 0.f, 0.f, 0.f};
    float lsum[4] = {};

    for (int kt = 0; kt <= qt; ++kt) {
      const int k0 = kt * 64;
      __syncthreads();

      {
        const short* kg = Kb + head + (size_t)(k0 + sr) * DD + sc;
        short8 a = *reinterpret_cast<const short8*>(kg);
        short8 b = *reinterpret_cast<const short8*>(kg + 8);
        *reinterpret_cast<short8*>(&Ks[sr * LDST + sc])     = a;
        *reinterpret_cast<short8*>(&Ks[sr * LDST + sc + 8]) = b;
        const short* vg = Vb + head + (size_t)sr * TT + k0 + sc;
        short8 c = *reinterpret_cast<const short8*>(vg);
        short8 d = *reinterpret_cast<const short8*>(vg + 8);
        *reinterpret_cast<short8*>(&Vt[sr * LDST + sc])     = c;
        *reinterpret_cast<short8*>(&Vt[sr * LDST + sc + 8]) = d;
      }
      __syncthreads();

      short8 kf[4][2];
#pragma unroll
      for (int nt = 0; nt < 4; ++nt)
#pragma unroll
        for (int kc = 0; kc < 2; ++kc)
          kf[nt][kc] = *reinterpret_cast<const short8*>(
              &Ks[(nt * 16 + l16) * LDST + kc * 32 + quad * 8]);

      f32x4 s[4];
#pragma unroll
      for (int nt = 0; nt < 4; ++nt) s[nt] = (f32x4){0.f, 0.f, 0.f, 0.f};
      __builtin_amdgcn_s_setprio(1);
#pragma unroll
      for (int nt = 0; nt < 4; ++nt)
#pragma unroll
        for (int kc = 0; kc < 2; ++kc)
          s[nt] = __builtin_amdgcn_mfma_f32_16x16x32_bf16(qf[kc], kf[nt][kc], s[nt], 0, 0, 0);
      __builtin_amdgcn_s_setprio(0);

      const int rowg_base = q0 + w * 16 + quad * 4;
#pragma unroll
      for (int r = 0; r < 4; ++r) {
        const int rowg = rowg_base + r;
        short pk[4];
#pragma unroll
        for (int nt = 0; nt < 4; ++nt) {
          float e = (k0 + nt * 16 + l16 <= rowg) ? __builtin_amdgcn_exp2f(s[nt][r]) : 0.f;
          lsum[r] += e;
          pk[nt] = f2bs(e);
        }
        short4 p4; p4.x = pk[0]; p4.y = pk[1]; p4.z = pk[2]; p4.w = pk[3];
        *reinterpret_cast<short4*>(&myP[(quad * 4 + r) * LDST + (l16 << 2)]) = p4;
      }

      __builtin_amdgcn_s_setprio(1);
#pragma unroll
      for (int cc = 0; cc < 2; ++cc) {
        short8 pf = *reinterpret_cast<const short8*>(
            &myP[l16 * LDST + cc * 32 + quad * 8]);
#pragma unroll
        for (int dt = 0; dt < 4; ++dt) {
          short8 vf = *reinterpret_cast<const short8*>(
              &Vt[(dt * 16 + l16) * LDST + cc * 32 + quad * 8]);
          O[dt] = __builtin_amdgcn_mfma_f32_16x16x32_bf16(pf, vf, O[dt], 0, 0, 0);
        }
      }
      __builtin_amdgcn_s_setprio(0);
    }

    float linv[4];
#pragma unroll
    for (int r = 0; r < 4; ++r) {
      float s = lsum[r];
      s += __shfl_xor(s, 1);
      s += __shfl_xor(s, 2);
      s += __shfl_xor(s, 4);
      s += __shfl_xor(s, 8);
      linv[r] = 1.f / s;
    }
#pragma unroll
    for (int dt = 0; dt < 4; ++dt)
#pragma unroll
      for (int r = 0; r < 4; ++r) {
        int tg = q0 + w * 16 + quad * 4 + r;
        Y[((size_t)bi * TT + tg) * CC + h * DD + dt * 16 + l16] =
            f2bs(O[dt][r] * linv[r]);
      }
  }
}

// ---------------------------------------------------------------------------
extern "C" void kernel_launch(void* const* d_in, const int* in_sizes, int n_in,
                              void* d_out, int out_size, void* d_ws, size_t ws_size,
                              hipStream_t stream) {
  const float* x  = (const float*)d_in[0];   // [4,2048,1024] fp32
  const float* Wa = (const float*)d_in[1];   // [1024,3072]  fp32
  const float* ba = (const float*)d_in[2];   // [3072]       fp32
  const float* Wp = (const float*)d_in[3];   // [1024,1024]  fp32
  const float* bp = (const float*)d_in[4];   // [1024]       fp32
  float* out = (float*)d_out;                // [4,2048,1024] fp32

  const size_t NELT = (size_t)BB * HH * TT * DD;   // 8388608
  short* qb  = (short*)d_ws;                       // bf16 [B,H,T,D] (pre-scaled)
  short* kb  = qb + NELT;                          // bf16 [B,H,T,D]
  short* vb  = kb + NELT;                          // bf16 [B,H,D,T] (t remapped)
  short* Xb  = vb + NELT;                          // [8192][1024] bf16
  short* Wat = Xb  + (size_t)BT * CC;              // [3072][1024] bf16 (Wa^T)
  short* Wpt = Wat + (size_t)CC * C3;              // [1024][1024] bf16 (Wp^T)
  short* Yb  = Wpt + (size_t)CC * CC;              // [8192][1024] bf16

  prep<<<dim3(64 + 256, 16), 256, 0, stream>>>(Wa, Wat, Wp, Wpt, x, Xb);

  gemm256<true> <<<dim3((C3 / 256) * (BT / 256)), 512, 0, stream>>>(Xb, Wat, ba, qb, kb, vb, nullptr);
  attn_mfma     <<<dim3(16, HH, BB),              256, 0, stream>>>(qb, kb, vb, Yb);
  gemm256<false><<<dim3((CC / 256) * (BT / 256)), 512, 0, stream>>>(Yb, Wpt, bp, nullptr, nullptr, nullptr, out);
}

// Round 4
// 270.244 us; speedup vs baseline: 1.1950x; 1.0503x over previous
//
#include <hip/hip_runtime.h>
#include <hip/hip_bf16.h>

#define BB 4
#define TT 2048
#define CC 1024
#define HH 16
#define DD 64
#define BT (BB*TT)   // 8192
#define C3 (3*CC)    // 3072
#define LDST 72      // attn LDS row stride in bf16 elems (144 B)
#define QSCALE 0.18033688011112042f   // 0.125 * log2(e)

typedef __attribute__((ext_vector_type(8))) short short8;
typedef __attribute__((ext_vector_type(4))) float f32x4;

__device__ __forceinline__ short f2bs(float f) {
  __hip_bfloat16 h = __float2bfloat16(f);
  return *reinterpret_cast<short*>(&h);
}

__device__ __forceinline__ void gl_lds16(const short* g, short* l) {
  __builtin_amdgcn_global_load_lds(
      (const __attribute__((address_space(1))) void*)(g),
      (__attribute__((address_space(3))) void*)(l), 16, 0, 0);
}

// ---------------------------------------------------------------------------
// P: single prep launch (verified R8, unchanged).
// ---------------------------------------------------------------------------
__global__ __launch_bounds__(256)
void prep(const float* __restrict__ Wa, short* __restrict__ Wat,
          const float* __restrict__ Wp, short* __restrict__ Wpt,
          const float* __restrict__ x, short* __restrict__ Xb)
{
  __shared__ float Lt[64][65];
  const int bx = blockIdx.x;
  if (bx >= 64) {
    size_t chunk = (size_t)(bx - 64) * 16 + blockIdx.y;
    size_t i = (chunk * 256 + threadIdx.x) * 8;
    float4 a = *reinterpret_cast<const float4*>(x + i);
    float4 b = *reinterpret_cast<const float4*>(x + i + 4);
    short8 o;
    o[0] = f2bs(a.x); o[1] = f2bs(a.y); o[2] = f2bs(a.z); o[3] = f2bs(a.w);
    o[4] = f2bs(b.x); o[5] = f2bs(b.y); o[6] = f2bs(b.z); o[7] = f2bs(b.w);
    *reinterpret_cast<short8*>(Xb + i) = o;
    return;
  }
  const bool isA = (bx < 48);
  const float* in  = isA ? Wa  : Wp;
  short*       out = isA ? Wat : Wpt;
  const int N  = isA ? C3 : CC;
  const int n0 = (isA ? bx : bx - 48) * 64;
  const int k0 = blockIdx.y * 64;
  const int cx = threadIdx.x & 15, rr = threadIdx.x >> 4;
#pragma unroll
  for (int p = 0; p < 4; ++p) {
    int kr = p * 16 + rr;
    float4 u = *reinterpret_cast<const float4*>(in + (size_t)(k0 + kr) * N + n0 + cx * 4);
    Lt[kr][cx * 4 + 0] = u.x;
    Lt[kr][cx * 4 + 1] = u.y;
    Lt[kr][cx * 4 + 2] = u.z;
    Lt[kr][cx * 4 + 3] = u.w;
  }
  __syncthreads();
#pragma unroll
  for (int p = 0; p < 4; ++p) {
    int nr = p * 16 + rr;
    short4 o;
    o.x = f2bs(Lt[cx * 4 + 0][nr]);
    o.y = f2bs(Lt[cx * 4 + 1][nr]);
    o.z = f2bs(Lt[cx * 4 + 2][nr]);
    o.w = f2bs(Lt[cx * 4 + 3][nr]);
    *reinterpret_cast<short4*>(out + (size_t)(n0 + nr) * CC + k0 + cx * 4) = o;
  }
}

// ---------------------------------------------------------------------------
// gemm256<QKV>: 256x256, BK=64, 8 waves, 8-phase counted-vmcnt schedule
// (R3-verified ledger, now ROLLED: unroll-by-2 steady loop + peeled tail;
// identical instruction schedule per phase, ~1/7 the code size).
//
// NEW this round: coalesced epilogue. sel = col0>>10 is uniform per block.
// After the last barrier the 128 KB LDS is free; two row-half passes:
//   pass hp: waves wr==hp scalar-write bf16(acc) into an LDS tile
//     q/k: EP[rl][264]   (row-major, pad 264 -> 528 B = 33*16, b128-clean)
//     v  : EPT[dcol][136] (transposed, t-group swizzle tp(rl) applied at
//          write; pad 136 -> 272 B = 17*16, b128-clean)
//   barrier; all 512 threads read b128 (bank-verified 2-way max = free) and
//   store short8: q/k = 128 B runs, v = 256 B contiguous per quarter-wave.
// Replaces the 32B-with-holes q/k stores and 2B/4KB-stride v scatter that
// inflated WRITE_SIZE to 86.9 MB (logical 48) and capped HBM at ~1.3 TB/s.
// ---------------------------------------------------------------------------
template<bool QKV>
__global__ __launch_bounds__(512, 2)
void gemm256(const short* __restrict__ A, const short* __restrict__ Bt,
             const float* __restrict__ bias,
             short* __restrict__ qb, short* __restrict__ kb, short* __restrict__ vb,
             float* __restrict__ out)
{
  __shared__ __align__(16) short SMEM[65536];   // 128 KB, carved manually

  const int t = threadIdx.x;
  const int lane = t & 63;
  const int l16 = lane & 15, quad = lane >> 4;
  const int w = t >> 6;
  const int wr = w >> 2, wc = w & 3;            // 2(M) x 4(N) wave grid

  // bijective XCD-chunked block swizzle (nwg % 8 == 0: 384 / 128)
  const int per   = gridDim.x >> 3;
  const int chunk = (blockIdx.x & 7) * per + (blockIdx.x >> 3);
  const int NBC   = QKV ? 12 : 4;
  const int brow  = chunk / NBC, bcol = chunk % NBC;
  const int row0  = brow * 256;
  const int col0  = bcol * 256;

  // A bufs at SMEM[0..32768), B bufs at SMEM[32768..65536)
  auto stageQ = [&](int bufS, int kcS, int tileS, bool isA) __attribute__((always_inline)) {
#pragma unroll
    for (int l = 0; l < 2; ++l) {
      int gq = l * 512 + t;                 // 16B-chunk id 0..1023
      int rq = gq >> 2;                     // row 0..255
      int g  = (gq & 3) ^ ((rq >> 1) & 3);  // conflict-free involution (R3-verified)
      if (isA) {
        gl_lds16(A + (size_t)(row0 + rq) * CC + tileS * 64 + kcS * 32 + g * 8,
                 &SMEM[bufS * 16384 + kcS * 8192 + gq * 8]);
      } else {
        gl_lds16(Bt + (size_t)(col0 + rq) * CC + tileS * 64 + kcS * 32 + g * 8,
                 &SMEM[32768 + bufS * 16384 + kcS * 8192 + gq * 8]);
      }
    }
  };

  f32x4 acc[8][4];
#pragma unroll
  for (int i = 0; i < 8; ++i)
#pragma unroll
    for (int j = 0; j < 4; ++j) acc[i][j] = (f32x4){0.f, 0.f, 0.f, 0.f};

  // one K-tile = 4 phases; tm: 0=steady, 1=u14 (stage ph0/1 only, ph3 vmcnt4),
  // 2=u15 (no stages, ph1 vmcnt0). Ledger identical to R3 (verified).
  auto kTile = [&](int u, int cb, int tm) __attribute__((always_inline)) {
    const short* Ac = &SMEM[cb * 16384];
    const short* Bc = &SMEM[32768 + cb * 16384];
    short8 bf[4];
#pragma unroll
    for (int ph = 0; ph < 4; ++ph) {
      const int kc = ph >> 1, q = ph & 1;
      if (q == 0) {
#pragma unroll
        for (int j = 0; j < 4; ++j) {
          int rb = wc * 64 + j * 16 + l16;
          bf[j] = *reinterpret_cast<const short8*>(
              &Bc[kc * 8192 + rb * 32 + (((quad ^ (rb >> 1)) & 3) << 3)]);
        }
      }
      short8 af[4];
#pragma unroll
      for (int iq = 0; iq < 4; ++iq) {
        int ra = wr * 128 + (q * 4 + iq) * 16 + l16;
        af[iq] = *reinterpret_cast<const short8*>(
            &Ac[kc * 8192 + ra * 32 + (((quad ^ (ra >> 1)) & 3) << 3)]);
      }

      if      (ph == 0) { if (tm < 2) stageQ(cb ^ 1, 1, u + 1, true ); }
      else if (ph == 1) { if (tm < 2) stageQ(cb ^ 1, 1, u + 1, false); }
      else if (ph == 2) { if (tm < 1) stageQ(cb,     0, u + 2, true ); }
      else              { if (tm < 1) stageQ(cb,     0, u + 2, false); }

      __builtin_amdgcn_s_barrier();
      asm volatile("s_waitcnt lgkmcnt(0)" ::: "memory");
      __builtin_amdgcn_sched_barrier(0);

      __builtin_amdgcn_s_setprio(1);
#pragma unroll
      for (int iq = 0; iq < 4; ++iq)
#pragma unroll
        for (int j = 0; j < 4; ++j)
          acc[q * 4 + iq][j] =
              __builtin_amdgcn_mfma_f32_16x16x32_bf16(af[iq], bf[j], acc[q * 4 + iq][j], 0, 0, 0);
      __builtin_amdgcn_s_setprio(0);

      if (ph == 1) {
        if (tm == 2) { asm volatile("s_waitcnt vmcnt(0)" ::: "memory"); }
        else         { asm volatile("s_waitcnt vmcnt(8)" ::: "memory"); }
      } else if (ph == 3) {
        if      (tm == 0) { asm volatile("s_waitcnt vmcnt(8)" ::: "memory"); }
        else if (tm == 1) { asm volatile("s_waitcnt vmcnt(4)" ::: "memory"); }
      }
      __builtin_amdgcn_s_barrier();
    }
  };

  // prologue: 6 quanta in steady-state issue order (12 loads/thread)
  stageQ(0, 0, 0, true);  stageQ(0, 0, 0, false);
  stageQ(0, 1, 0, true);  stageQ(0, 1, 0, false);
  stageQ(1, 0, 1, true);  stageQ(1, 0, 1, false);
  asm volatile("s_waitcnt vmcnt(8)" ::: "memory");
  __builtin_amdgcn_s_barrier();

  for (int u = 0; u < 14; u += 2) {   // rolled steady state
    kTile(u,     0, 0);
    kTile(u + 1, 1, 0);
  }
  kTile(14, 0, 1);
  kTile(15, 1, 2);

  if constexpr (QKV) {
    const int sel = col0 >> 10;                    // uniform per block
#pragma unroll
    for (int hp = 0; hp < 2; ++hp) {
      __syncthreads();                             // LDS free / prev pass reads done
      if (wr == hp) {
#pragma unroll
        for (int j = 0; j < 4; ++j) {
          const int colL = wc * 64 + j * 16 + l16;           // 0..255
          const float bv = bias[col0 + colL];
#pragma unroll
          for (int i = 0; i < 8; ++i)
#pragma unroll
            for (int r = 0; r < 4; ++r) {
              const int rl = i * 16 + quad * 4 + r;          // 0..127
              float val = acc[i][j][r] + bv;
              if (sel == 0) val *= QSCALE;
              short vs = f2bs(val);
              if (sel == 2) {
                // transposed + t-group swizzle applied at write (base 64-aligned)
                int tpl = (rl & ~63) | ((rl & 15) << 2) | ((rl >> 4) & 3);
                SMEM[colL * 136 + tpl] = vs;
              } else {
                SMEM[rl * 264 + colL] = vs;
              }
            }
        }
      }
      __syncthreads();
      const int Rbase = row0 + hp * 128;           // 128-aligned -> single bi
      const int bi = Rbase >> 11;
      if (sel != 2) {
        short* __restrict__ dstB = (sel == 0) ? qb : kb;
#pragma unroll
        for (int rep = 0; rep < 8; ++rep) {
          int slot = rep * 512 + t;
          int rl = slot >> 5, ch = slot & 31;
          short8 vv = *reinterpret_cast<const short8*>(&SMEM[rl * 264 + ch * 8]);
          int tt  = (Rbase & 2047) + rl;
          int cin = (col0 + ch * 8) & 1023;
          int h = cin >> 6, dd = cin & 63;
          *reinterpret_cast<short8*>(
              &dstB[(((size_t)(bi * HH + h)) * TT + tt) * DD + dd]) = vv;
        }
      } else {
#pragma unroll
        for (int rep = 0; rep < 8; ++rep) {
          int slot = rep * 512 + t;
          int dcol = slot >> 4, ch = slot & 15;
          short8 vv = *reinterpret_cast<const short8*>(&SMEM[dcol * 136 + ch * 8]);
          int cin = (col0 + dcol) & 1023;
          int h = cin >> 6, dd = cin & 63;
          int ttb = (Rbase & 2047) + ch * 8;
          *reinterpret_cast<short8*>(
              &vb[(((size_t)(bi * HH + h)) * DD + dd) * TT + ttb]) = vv;
        }
      }
    }
  } else {
#pragma unroll
    for (int j = 0; j < 4; ++j) {
      int col = col0 + wc * 64 + j * 16 + l16;
      float bv = bias[col];
#pragma unroll
      for (int i = 0; i < 8; ++i)
#pragma unroll
        for (int r = 0; r < 4; ++r) {
          int row = row0 + wr * 128 + i * 16 + quad * 4 + r;
          out[(size_t)row * CC + col] = acc[i][j][r] + bv;
        }
    }
  }
}

// ---------------------------------------------------------------------------
// K2: MFMA flash attention (verified R6 body + XCD remap + setprio).
// ---------------------------------------------------------------------------
__global__ __launch_bounds__(256, 4)
void attn_mfma(const short* __restrict__ Qb, const short* __restrict__ Kb,
               const short* __restrict__ Vb, short* __restrict__ Y)
{
  __shared__ __align__(16) short Ks[64 * LDST];
  __shared__ __align__(16) short Vt[64 * LDST];
  __shared__ __align__(16) short Pw[4 * 16 * LDST];

  const int t    = threadIdx.x;
  const int w    = t >> 6;
  const int lane = t & 63;
  const int l16  = lane & 15;
  const int quad = lane >> 4;

  const int linear = blockIdx.x + 16 * (blockIdx.y + 16 * blockIdx.z);
  const int nb  = (linear & 7) * 128 + (linear >> 3);
  const int qt0 = nb & 15;
  const int h   = (nb >> 4) & 15;
  const int bi  = nb >> 8;
  const size_t head = (size_t)(bi * HH + h) * TT * DD;

  short* myP = &Pw[w * 16 * LDST];
  const int sr = t >> 2;
  const int sc = (t & 3) << 4;

  const int qts[2] = { qt0, 31 - qt0 };

#pragma unroll
  for (int half = 0; half < 2; ++half) {
    const int qt = qts[half];
    const int q0 = qt * 64;

    short8 qf[2];
#pragma unroll
    for (int kc = 0; kc < 2; ++kc)
      qf[kc] = *reinterpret_cast<const short8*>(
          &Qb[head + (size_t)(q0 + w * 16 + l16) * DD + kc * 32 + quad * 8]);

    f32x4 O[4];
#pragma unroll
    for (int dt = 0; dt < 4; ++dt) O[dt] = (f32x4){0.f, 0.f, 0.f, 0.f};
    float lsum[4] = {};

    for (int kt = 0; kt <= qt; ++kt) {
      const int k0 = kt * 64;
      __syncthreads();

      {
        const short* kg = Kb + head + (size_t)(k0 + sr) * DD + sc;
        short8 a = *reinterpret_cast<const short8*>(kg);
        short8 b = *reinterpret_cast<const short8*>(kg + 8);
        *reinterpret_cast<short8*>(&Ks[sr * LDST + sc])     = a;
        *reinterpret_cast<short8*>(&Ks[sr * LDST + sc + 8]) = b;
        const short* vg = Vb + head + (size_t)sr * TT + k0 + sc;
        short8 c = *reinterpret_cast<const short8*>(vg);
        short8 d = *reinterpret_cast<const short8*>(vg + 8);
        *reinterpret_cast<short8*>(&Vt[sr * LDST + sc])     = c;
        *reinterpret_cast<short8*>(&Vt[sr * LDST + sc + 8]) = d;
      }
      __syncthreads();

      short8 kf[4][2];
#pragma unroll
      for (int nt = 0; nt < 4; ++nt)
#pragma unroll
        for (int kc = 0; kc < 2; ++kc)
          kf[nt][kc] = *reinterpret_cast<const short8*>(
              &Ks[(nt * 16 + l16) * LDST + kc * 32 + quad * 8]);

      f32x4 s[4];
#pragma unroll
      for (int nt = 0; nt < 4; ++nt) s[nt] = (f32x4){0.f, 0.f, 0.f, 0.f};
      __builtin_amdgcn_s_setprio(1);
#pragma unroll
      for (int nt = 0; nt < 4; ++nt)
#pragma unroll
        for (int kc = 0; kc < 2; ++kc)
          s[nt] = __builtin_amdgcn_mfma_f32_16x16x32_bf16(qf[kc], kf[nt][kc], s[nt], 0, 0, 0);
      __builtin_amdgcn_s_setprio(0);

      const int rowg_base = q0 + w * 16 + quad * 4;
#pragma unroll
      for (int r = 0; r < 4; ++r) {
        const int rowg = rowg_base + r;
        short pk[4];
#pragma unroll
        for (int nt = 0; nt < 4; ++nt) {
          float e = (k0 + nt * 16 + l16 <= rowg) ? __builtin_amdgcn_exp2f(s[nt][r]) : 0.f;
          lsum[r] += e;
          pk[nt] = f2bs(e);
        }
        short4 p4; p4.x = pk[0]; p4.y = pk[1]; p4.z = pk[2]; p4.w = pk[3];
        *reinterpret_cast<short4*>(&myP[(quad * 4 + r) * LDST + (l16 << 2)]) = p4;
      }

      __builtin_amdgcn_s_setprio(1);
#pragma unroll
      for (int cc = 0; cc < 2; ++cc) {
        short8 pf = *reinterpret_cast<const short8*>(
            &myP[l16 * LDST + cc * 32 + quad * 8]);
#pragma unroll
        for (int dt = 0; dt < 4; ++dt) {
          short8 vf = *reinterpret_cast<const short8*>(
              &Vt[(dt * 16 + l16) * LDST + cc * 32 + quad * 8]);
          O[dt] = __builtin_amdgcn_mfma_f32_16x16x32_bf16(pf, vf, O[dt], 0, 0, 0);
        }
      }
      __builtin_amdgcn_s_setprio(0);
    }

    float linv[4];
#pragma unroll
    for (int r = 0; r < 4; ++r) {
      float s = lsum[r];
      s += __shfl_xor(s, 1);
      s += __shfl_xor(s, 2);
      s += __shfl_xor(s, 4);
      s += __shfl_xor(s, 8);
      linv[r] = 1.f / s;
    }
#pragma unroll
    for (int dt = 0; dt < 4; ++dt)
#pragma unroll
      for (int r = 0; r < 4; ++r) {
        int tg = q0 + w * 16 + quad * 4 + r;
        Y[((size_t)bi * TT + tg) * CC + h * DD + dt * 16 + l16] =
            f2bs(O[dt][r] * linv[r]);
      }
  }
}

// ---------------------------------------------------------------------------
extern "C" void kernel_launch(void* const* d_in, const int* in_sizes, int n_in,
                              void* d_out, int out_size, void* d_ws, size_t ws_size,
                              hipStream_t stream) {
  const float* x  = (const float*)d_in[0];   // [4,2048,1024] fp32
  const float* Wa = (const float*)d_in[1];   // [1024,3072]  fp32
  const float* ba = (const float*)d_in[2];   // [3072]       fp32
  const float* Wp = (const float*)d_in[3];   // [1024,1024]  fp32
  const float* bp = (const float*)d_in[4];   // [1024]       fp32
  float* out = (float*)d_out;                // [4,2048,1024] fp32

  const size_t NELT = (size_t)BB * HH * TT * DD;   // 8388608
  short* qb  = (short*)d_ws;                       // bf16 [B,H,T,D] (pre-scaled)
  short* kb  = qb + NELT;                          // bf16 [B,H,T,D]
  short* vb  = kb + NELT;                          // bf16 [B,H,D,T] (t remapped)
  short* Xb  = vb + NELT;                          // [8192][1024] bf16
  short* Wat = Xb  + (size_t)BT * CC;              // [3072][1024] bf16 (Wa^T)
  short* Wpt = Wat + (size_t)CC * C3;              // [1024][1024] bf16 (Wp^T)
  short* Yb  = Wpt + (size_t)CC * CC;              // [8192][1024] bf16

  prep<<<dim3(64 + 256, 16), 256, 0, stream>>>(Wa, Wat, Wp, Wpt, x, Xb);

  gemm256<true> <<<dim3((C3 / 256) * (BT / 256)), 512, 0, stream>>>(Xb, Wat, ba, qb, kb, vb, nullptr);
  attn_mfma     <<<dim3(16, HH, BB),              256, 0, stream>>>(qb, kb, vb, Yb);
  gemm256<false><<<dim3((CC / 256) * (BT / 256)), 512, 0, stream>>>(Yb, Wpt, bp, nullptr, nullptr, nullptr, out);
}

// Round 6
// 250.908 us; speedup vs baseline: 1.2871x; 1.0771x over previous
//
#include <hip/hip_runtime.h>
#include <hip/hip_bf16.h>

#define BB 4
#define TT 2048
#define CC 1024
#define HH 16
#define DD 64
#define BT (BB*TT)   // 8192
#define C3 (3*CC)    // 3072
#define LDST 72      // attn P-buffer row stride in bf16 elems (144 B)
#define QSCALE 0.18033688011112042f   // 0.125 * log2(e)

typedef __attribute__((ext_vector_type(8))) short short8;
typedef __attribute__((ext_vector_type(4))) float f32x4;

__device__ __forceinline__ short f2bs(float f) {
  __hip_bfloat16 h = __float2bfloat16(f);
  return *reinterpret_cast<short*>(&h);
}

__device__ __forceinline__ void gl_lds16(const short* g, short* l) {
  __builtin_amdgcn_global_load_lds(
      (const __attribute__((address_space(1))) void*)(g),
      (__attribute__((address_space(3))) void*)(l), 16, 0, 0);
}

// ---------------------------------------------------------------------------
// P: single prep launch (verified R8, unchanged).
// ---------------------------------------------------------------------------
__global__ __launch_bounds__(256)
void prep(const float* __restrict__ Wa, short* __restrict__ Wat,
          const float* __restrict__ Wp, short* __restrict__ Wpt,
          const float* __restrict__ x, short* __restrict__ Xb)
{
  __shared__ float Lt[64][65];
  const int bx = blockIdx.x;
  if (bx >= 64) {
    size_t chunk = (size_t)(bx - 64) * 16 + blockIdx.y;
    size_t i = (chunk * 256 + threadIdx.x) * 8;
    float4 a = *reinterpret_cast<const float4*>(x + i);
    float4 b = *reinterpret_cast<const float4*>(x + i + 4);
    short8 o;
    o[0] = f2bs(a.x); o[1] = f2bs(a.y); o[2] = f2bs(a.z); o[3] = f2bs(a.w);
    o[4] = f2bs(b.x); o[5] = f2bs(b.y); o[6] = f2bs(b.z); o[7] = f2bs(b.w);
    *reinterpret_cast<short8*>(Xb + i) = o;
    return;
  }
  const bool isA = (bx < 48);
  const float* in  = isA ? Wa  : Wp;
  short*       out = isA ? Wat : Wpt;
  const int N  = isA ? C3 : CC;
  const int n0 = (isA ? bx : bx - 48) * 64;
  const int k0 = blockIdx.y * 64;
  const int cx = threadIdx.x & 15, rr = threadIdx.x >> 4;
#pragma unroll
  for (int p = 0; p < 4; ++p) {
    int kr = p * 16 + rr;
    float4 u = *reinterpret_cast<const float4*>(in + (size_t)(k0 + kr) * N + n0 + cx * 4);
    Lt[kr][cx * 4 + 0] = u.x;
    Lt[kr][cx * 4 + 1] = u.y;
    Lt[kr][cx * 4 + 2] = u.z;
    Lt[kr][cx * 4 + 3] = u.w;
  }
  __syncthreads();
#pragma unroll
  for (int p = 0; p < 4; ++p) {
    int nr = p * 16 + rr;
    short4 o;
    o.x = f2bs(Lt[cx * 4 + 0][nr]);
    o.y = f2bs(Lt[cx * 4 + 1][nr]);
    o.z = f2bs(Lt[cx * 4 + 2][nr]);
    o.w = f2bs(Lt[cx * 4 + 3][nr]);
    *reinterpret_cast<short4*>(out + (size_t)(n0 + nr) * CC + k0 + cx * 4) = o;
  }
}

// ---------------------------------------------------------------------------
// gemm256<QKV, NBF>: 256 x (NBF*64) tile, BK=64, 8 waves (2M x 4N), 8-phase
// counted-vmcnt schedule (R3/R4-verified ledger, parameterized).
//   NBF=4: 256x256 (qkv, 384 blocks);  NBF=2: 256x128 (proj, 256 blocks
//   = exactly 1/CU, fixing the half-idle 128-block proj grid).
// vmcnt ledger: A-quantum = 2 loads/thread, B-quantum = NBF/2 loads.
//   steady keep = newest 4 quanta = 4 + NBF loads -> vmcnt(8)/vmcnt(6)
//   tail u14.ph3 keep = 2 quanta = 2 + NBF/2   -> vmcnt(4)/vmcnt(3)
// QKV epilogue writes kb/vb in 8KB-per-(head,kt) TILES with the attn
// bank-swizzle baked in at rest (slot c' = g ^ ((row>>1)&7)), so attn can
// stage with linear global_load_lds copies.
// ---------------------------------------------------------------------------
template<bool QKV, int NBF>
__global__ __launch_bounds__(512, 2)
void gemm256(const short* __restrict__ A, const short* __restrict__ Bt,
             const float* __restrict__ bias,
             short* __restrict__ qb, short* __restrict__ kb, short* __restrict__ vb,
             float* __restrict__ out)
{
  constexpr int BQ   = NBF * 64 * 32;        // elems per B (buf,kc) region
  constexpr int BOFF = 32768;                // A region: [2][2][256][32] elems
  __shared__ __align__(16) short SMEM[BOFF + 4 * BQ];

  const int t = threadIdx.x;
  const int lane = t & 63;
  const int l16 = lane & 15, quad = lane >> 4;
  const int w = t >> 6;
  const int wr = w >> 2, wc = w & 3;            // 2(M) x 4(N) wave grid

  // bijective XCD-chunked block swizzle (nwg % 8 == 0: 384 / 256)
  const int per   = gridDim.x >> 3;
  const int chunk = (blockIdx.x & 7) * per + (blockIdx.x >> 3);
  const int NBC   = QKV ? 12 : (CC / (NBF * 64));
  const int brow  = chunk / NBC, bcol = chunk % NBC;
  const int row0  = brow * 256;
  const int col0  = bcol * (NBF * 64);

  auto stageQA = [&](int bufS, int kcS, int tileS) __attribute__((always_inline)) {
#pragma unroll
    for (int l = 0; l < 2; ++l) {
      int gq = l * 512 + t;
      int rq = gq >> 2;
      int g  = (gq & 3) ^ ((rq >> 1) & 3);
      gl_lds16(A + (size_t)(row0 + rq) * CC + tileS * 64 + kcS * 32 + g * 8,
               &SMEM[bufS * 16384 + kcS * 8192 + gq * 8]);
    }
  };
  auto stageQB = [&](int bufS, int kcS, int tileS) __attribute__((always_inline)) {
#pragma unroll
    for (int l = 0; l < NBF / 2; ++l) {
      int gq = l * 512 + t;
      int rq = gq >> 2;
      int g  = (gq & 3) ^ ((rq >> 1) & 3);
      gl_lds16(Bt + (size_t)(col0 + rq) * CC + tileS * 64 + kcS * 32 + g * 8,
               &SMEM[BOFF + bufS * 2 * BQ + kcS * BQ + gq * 8]);
    }
  };

  f32x4 acc[8][NBF];
#pragma unroll
  for (int i = 0; i < 8; ++i)
#pragma unroll
    for (int j = 0; j < NBF; ++j) acc[i][j] = (f32x4){0.f, 0.f, 0.f, 0.f};

  auto kTile = [&](int u, int cb, int tm) __attribute__((always_inline)) {
    const short* Ac = &SMEM[cb * 16384];
    const short* Bc = &SMEM[BOFF + cb * 2 * BQ];
    short8 bf[NBF];
#pragma unroll
    for (int ph = 0; ph < 4; ++ph) {
      const int kc = ph >> 1, q = ph & 1;
      if (q == 0) {
#pragma unroll
        for (int j = 0; j < NBF; ++j) {
          int rb = wc * (NBF * 16) + j * 16 + l16;
          bf[j] = *reinterpret_cast<const short8*>(
              &Bc[kc * BQ + rb * 32 + (((quad ^ (rb >> 1)) & 3) << 3)]);
        }
      }
      short8 af[4];
#pragma unroll
      for (int iq = 0; iq < 4; ++iq) {
        int ra = wr * 128 + (q * 4 + iq) * 16 + l16;
        af[iq] = *reinterpret_cast<const short8*>(
            &Ac[kc * 8192 + ra * 32 + (((quad ^ (ra >> 1)) & 3) << 3)]);
      }

      if      (ph == 0) { if (tm < 2) stageQA(cb ^ 1, 1, u + 1); }
      else if (ph == 1) { if (tm < 2) stageQB(cb ^ 1, 1, u + 1); }
      else if (ph == 2) { if (tm < 1) stageQA(cb,     0, u + 2); }
      else              { if (tm < 1) stageQB(cb,     0, u + 2); }

      __builtin_amdgcn_s_barrier();
      asm volatile("s_waitcnt lgkmcnt(0)" ::: "memory");
      __builtin_amdgcn_sched_barrier(0);

      __builtin_amdgcn_s_setprio(1);
#pragma unroll
      for (int iq = 0; iq < 4; ++iq)
#pragma unroll
        for (int j = 0; j < NBF; ++j)
          acc[q * 4 + iq][j] =
              __builtin_amdgcn_mfma_f32_16x16x32_bf16(af[iq], bf[j], acc[q * 4 + iq][j], 0, 0, 0);
      __builtin_amdgcn_s_setprio(0);

      if (ph == 1) {
        if (tm == 2) { asm volatile("s_waitcnt vmcnt(0)" ::: "memory"); }
        else if (NBF == 4) { asm volatile("s_waitcnt vmcnt(8)" ::: "memory"); }
        else               { asm volatile("s_waitcnt vmcnt(6)" ::: "memory"); }
      } else if (ph == 3) {
        if (tm == 0) {
          if (NBF == 4) { asm volatile("s_waitcnt vmcnt(8)" ::: "memory"); }
          else          { asm volatile("s_waitcnt vmcnt(6)" ::: "memory"); }
        } else if (tm == 1) {
          if (NBF == 4) { asm volatile("s_waitcnt vmcnt(4)" ::: "memory"); }
          else          { asm volatile("s_waitcnt vmcnt(3)" ::: "memory"); }
        }
      }
      __builtin_amdgcn_s_barrier();
    }
  };

  // prologue: 6 quanta in steady-state issue order
  stageQA(0, 0, 0);  stageQB(0, 0, 0);
  stageQA(0, 1, 0);  stageQB(0, 1, 0);
  stageQA(1, 0, 1);  stageQB(1, 0, 1);
  if (NBF == 4) { asm volatile("s_waitcnt vmcnt(8)" ::: "memory"); }
  else          { asm volatile("s_waitcnt vmcnt(6)" ::: "memory"); }
  __builtin_amdgcn_s_barrier();

  for (int u = 0; u < 14; u += 2) {
    kTile(u,     0, 0);
    kTile(u + 1, 1, 0);
  }
  kTile(14, 0, 1);
  kTile(15, 1, 2);

  if constexpr (QKV) {
    const int sel = col0 >> 10;                    // uniform per block
#pragma unroll
    for (int hp = 0; hp < 2; ++hp) {
      __syncthreads();
      if (wr == hp) {
#pragma unroll
        for (int j = 0; j < 4; ++j) {
          const int colL = wc * 64 + j * 16 + l16;           // 0..255
          const float bv = bias[col0 + colL];
#pragma unroll
          for (int i = 0; i < 8; ++i)
#pragma unroll
            for (int r = 0; r < 4; ++r) {
              const int rl = i * 16 + quad * 4 + r;          // 0..127
              float val = acc[i][j][r] + bv;
              if (sel == 0) val *= QSCALE;
              short vs = f2bs(val);
              if (sel == 2) {
                int tpl = (rl & ~63) | ((rl & 15) << 2) | ((rl >> 4) & 3);
                SMEM[colL * 136 + tpl] = vs;
              } else {
                SMEM[rl * 264 + colL] = vs;
              }
            }
        }
      }
      __syncthreads();
      const int Rbase = row0 + hp * 128;           // 128-aligned -> single bi
      const int bi = Rbase >> 11;
      if (sel == 0) {
        // q: flat [B,H,T,D] (128 B runs)
#pragma unroll
        for (int rep = 0; rep < 8; ++rep) {
          int slot = rep * 512 + t;
          int rl = slot >> 5, ch = slot & 31;
          short8 vv = *reinterpret_cast<const short8*>(&SMEM[rl * 264 + ch * 8]);
          int tt  = (Rbase & 2047) + rl;
          int cin = (col0 + ch * 8) & 1023;
          int hh = cin >> 6, dd = cin & 63;
          *reinterpret_cast<short8*>(
              &qb[(((size_t)(bi * HH + hh)) * TT + tt) * DD + dd]) = vv;
        }
      } else if (sel == 1) {
        // k: 8KB tiles [hb][kt][row=t&63][8 chunk-slots], slot = g ^ ((rt>>1)&7)
#pragma unroll
        for (int rep = 0; rep < 8; ++rep) {
          int slot = rep * 512 + t;
          int rl = slot >> 5, ch = slot & 31;
          short8 vv = *reinterpret_cast<const short8*>(&SMEM[rl * 264 + ch * 8]);
          int tt  = (Rbase & 2047) + rl;
          int cin = (col0 + ch * 8) & 1023;
          int hh = cin >> 6;
          int rt = tt & 63;
          int cs = ((cin >> 3) & 7) ^ ((rt >> 1) & 7);
          size_t tile = (size_t)(bi * HH + hh) * 32 + (tt >> 6);
          *reinterpret_cast<short8*>(&kb[tile * 4096 + rt * 64 + cs * 8]) = vv;
        }
      } else {
        // v: 8KB tiles [hb][kt][row=dd][8 chunk-slots over t-permuted cols]
#pragma unroll
        for (int rep = 0; rep < 8; ++rep) {
          int slot = rep * 512 + t;
          int dcol = slot >> 4, ch = slot & 15;
          short8 vv = *reinterpret_cast<const short8*>(&SMEM[dcol * 136 + ch * 8]);
          int cin = (col0 + dcol) & 1023;
          int hh = cin >> 6, dd = cin & 63;
          int ktv = ((Rbase & 2047) >> 6) + (ch >> 3);
          int cs  = (ch & 7) ^ ((dd >> 1) & 7);
          *reinterpret_cast<short8*>(
              &vb[((size_t)(bi * HH + hh) * 32 + ktv) * 4096 + dd * 64 + cs * 8]) = vv;
        }
      }
    }
  } else {
#pragma unroll
    for (int j = 0; j < NBF; ++j) {
      int col = col0 + wc * (NBF * 16) + j * 16 + l16;
      float bv = bias[col];
#pragma unroll
      for (int i = 0; i < 8; ++i)
#pragma unroll
        for (int r = 0; r < 4; ++r) {
          int row = row0 + wr * 128 + i * 16 + quad * 4 + r;
          out[(size_t)row * CC + col] = acc[i][j][r] + bv;
        }
    }
  }
}

// ---------------------------------------------------------------------------
// K2: MFMA flash attention, restaged. K/V live in 8KB-per-(head,kt) tiles
// with the bank-swizzle baked in at rest -> staging = linear gl_lds copies
// (no VGPR roundtrip, no ds_writes). K double-buffered; V staged under QK;
// counted-vmcnt 2-barrier ledger:
//   iter kt (steady): in-flight {K(kt+1), V(kt)} (each 2 loads, >=1 phase old)
//     QK^T(Kd[kt&1]) ; softmax -> Pw
//     vmcnt(0); barrier1        // all waves' loads landed + Kd[p] reads done
//     issue K(kt+2) -> Kd[kt&1]
//     PV(Vt, Pw) ; barrier2     // Vt reads done block-wide
//     issue V(kt+1) -> Vt
// LDS: Kd 2x8KB + Vt 8KB + Pw 9KB = 33 KB -> 4 blocks/CU.
// Reads XOR slot = c ^ ((row>>1)&7): quarter-wave b128 covers all 32 banks
// exactly 2x = free (replaces the LDST=72 padding for K/V).
// ---------------------------------------------------------------------------
__global__ __launch_bounds__(256, 4)
void attn_mfma(const short* __restrict__ Qb, const short* __restrict__ Kb,
               const short* __restrict__ Vb, short* __restrict__ Y)
{
  __shared__ __align__(16) short Kd[2][4096];
  __shared__ __align__(16) short Vt[4096];
  __shared__ __align__(16) short Pw[4 * 16 * LDST];

  const int t    = threadIdx.x;
  const int w    = t >> 6;
  const int lane = t & 63;
  const int l16  = lane & 15;
  const int quad = lane >> 4;

  const int linear = blockIdx.x + 16 * (blockIdx.y + 16 * blockIdx.z);
  const int nb  = (linear & 7) * 128 + (linear >> 3);
  const int qt0 = nb & 15;
  const int h   = (nb >> 4) & 15;
  const int bi  = nb >> 8;
  const size_t head = (size_t)(bi * HH + h) * TT * DD;   // == tile_base*4096

  short* myP = &Pw[w * 16 * LDST];

  auto stageK = [&](int kt, int p) __attribute__((always_inline)) {
    const short* src = Kb + head + (size_t)kt * 4096;
    gl_lds16(src + t * 8,        &Kd[p][t * 8]);
    gl_lds16(src + 2048 + t * 8, &Kd[p][2048 + t * 8]);
  };
  auto stageV = [&](int kt) __attribute__((always_inline)) {
    const short* src = Vb + head + (size_t)kt * 4096;
    gl_lds16(src + t * 8,        &Vt[t * 8]);
    gl_lds16(src + 2048 + t * 8, &Vt[2048 + t * 8]);
  };

  const int qts[2] = { qt0, 31 - qt0 };

#pragma unroll
  for (int half = 0; half < 2; ++half) {
    const int qt = qts[half];
    const int q0 = qt * 64;

    short8 qf[2];
#pragma unroll
    for (int kc = 0; kc < 2; ++kc)
      qf[kc] = *reinterpret_cast<const short8*>(
          &Qb[head + (size_t)(q0 + w * 16 + l16) * DD + kc * 32 + quad * 8]);

    f32x4 O[4];
#pragma unroll
    for (int dt = 0; dt < 4; ++dt) O[dt] = (f32x4){0.f, 0.f, 0.f, 0.f};
    float lsum[4] = {};

    // prologue: K(0), V(0), [K(1)]; certify K(0)
    stageK(0, 0);
    stageV(0);
    if (qt >= 1) {
      stageK(1, 1);
      asm volatile("s_waitcnt vmcnt(4)" ::: "memory");
    } else {
      asm volatile("s_waitcnt vmcnt(2)" ::: "memory");
    }
    __builtin_amdgcn_s_barrier();

    for (int kt = 0; kt <= qt; ++kt) {
      const int p  = kt & 1;
      const int k0 = kt * 64;

      // QK^T from Kd[p] (certified at prev iter's vmcnt(0)+barrier1 / prologue)
      short8 kf[4][2];
#pragma unroll
      for (int nt = 0; nt < 4; ++nt)
#pragma unroll
        for (int kc = 0; kc < 2; ++kc) {
          int r = nt * 16 + l16;
          int c = kc * 4 + quad;
          kf[nt][kc] = *reinterpret_cast<const short8*>(
              &Kd[p][r * 64 + ((c ^ ((r >> 1) & 7)) << 3)]);
        }

      f32x4 s[4];
#pragma unroll
      for (int nt = 0; nt < 4; ++nt) s[nt] = (f32x4){0.f, 0.f, 0.f, 0.f};
      __builtin_amdgcn_s_setprio(1);
#pragma unroll
      for (int nt = 0; nt < 4; ++nt)
#pragma unroll
        for (int kc = 0; kc < 2; ++kc)
          s[nt] = __builtin_amdgcn_mfma_f32_16x16x32_bf16(qf[kc], kf[nt][kc], s[nt], 0, 0, 0);
      __builtin_amdgcn_s_setprio(0);

      const int rowg_base = q0 + w * 16 + quad * 4;
#pragma unroll
      for (int r = 0; r < 4; ++r) {
        const int rowg = rowg_base + r;
        short pk[4];
#pragma unroll
        for (int nt = 0; nt < 4; ++nt) {
          float e = (k0 + nt * 16 + l16 <= rowg) ? __builtin_amdgcn_exp2f(s[nt][r]) : 0.f;
          lsum[r] += e;
          pk[nt] = f2bs(e);
        }
        short4 p4; p4.x = pk[0]; p4.y = pk[1]; p4.z = pk[2]; p4.w = pk[3];
        *reinterpret_cast<short4*>(&myP[(quad * 4 + r) * LDST + (l16 << 2)]) = p4;
      }

      asm volatile("s_waitcnt vmcnt(0)" ::: "memory");  // V(kt), K(kt+1) landed
      __builtin_amdgcn_s_barrier();                     // barrier1 (block-wide)

      if (kt + 2 <= qt) stageK(kt + 2, p);              // Kd[p] free after barrier1

      __builtin_amdgcn_s_setprio(1);
#pragma unroll
      for (int cc = 0; cc < 2; ++cc) {
        short8 pf = *reinterpret_cast<const short8*>(
            &myP[l16 * LDST + cc * 32 + quad * 8]);
#pragma unroll
        for (int dt = 0; dt < 4; ++dt) {
          int r = dt * 16 + l16;
          int c = cc * 4 + quad;
          short8 vf = *reinterpret_cast<const short8*>(
              &Vt[r * 64 + ((c ^ ((r >> 1) & 7)) << 3)]);
          O[dt] = __builtin_amdgcn_mfma_f32_16x16x32_bf16(pf, vf, O[dt], 0, 0, 0);
        }
      }
      __builtin_amdgcn_s_setprio(0);

      __builtin_amdgcn_s_barrier();                     // barrier2: Vt free
      if (kt + 1 <= qt) stageV(kt + 1);
    }

    float linv[4];
#pragma unroll
    for (int r = 0; r < 4; ++r) {
      float s = lsum[r];
      s += __shfl_xor(s, 1);
      s += __shfl_xor(s, 2);
      s += __shfl_xor(s, 4);
      s += __shfl_xor(s, 8);
      linv[r] = 1.f / s;
    }
#pragma unroll
    for (int dt = 0; dt < 4; ++dt)
#pragma unroll
      for (int r = 0; r < 4; ++r) {
        int tg = q0 + w * 16 + quad * 4 + r;
        Y[((size_t)bi * TT + tg) * CC + h * DD + dt * 16 + l16] =
            f2bs(O[dt][r] * linv[r]);
      }
  }
}

// ---------------------------------------------------------------------------
extern "C" void kernel_launch(void* const* d_in, const int* in_sizes, int n_in,
                              void* d_out, int out_size, void* d_ws, size_t ws_size,
                              hipStream_t stream) {
  const float* x  = (const float*)d_in[0];   // [4,2048,1024] fp32
  const float* Wa = (const float*)d_in[1];   // [1024,3072]  fp32
  const float* ba = (const float*)d_in[2];   // [3072]       fp32
  const float* Wp = (const float*)d_in[3];   // [1024,1024]  fp32
  const float* bp = (const float*)d_in[4];   // [1024]       fp32
  float* out = (float*)d_out;                // [4,2048,1024] fp32

  const size_t NELT = (size_t)BB * HH * TT * DD;   // 8388608
  short* qb  = (short*)d_ws;                       // bf16 [B,H,T,D] (pre-scaled)
  short* kb  = qb + NELT;                          // bf16 tiles [B*H][32][64][64] swz
  short* vb  = kb + NELT;                          // bf16 tiles [B*H][32][64][64] swz
  short* Xb  = vb + NELT;                          // [8192][1024] bf16
  short* Wat = Xb  + (size_t)BT * CC;              // [3072][1024] bf16 (Wa^T)
  short* Wpt = Wat + (size_t)CC * C3;              // [1024][1024] bf16 (Wp^T)
  short* Yb  = Wpt + (size_t)CC * CC;              // [8192][1024] bf16

  prep<<<dim3(64 + 256, 16), 256, 0, stream>>>(Wa, Wat, Wp, Wpt, x, Xb);

  gemm256<true, 4> <<<dim3((C3 / 256) * (BT / 256)), 512, 0, stream>>>(Xb, Wat, ba, qb, kb, vb, nullptr);
  attn_mfma        <<<dim3(16, HH, BB),              256, 0, stream>>>(qb, kb, vb, Yb);
  gemm256<false, 2><<<dim3((CC / 128) * (BT / 256)), 512, 0, stream>>>(Yb, Wpt, bp, nullptr, nullptr, nullptr, out);
}